// Round 4
// baseline (84.917 us; speedup 1.0000x reference)
//
#include <hip/hip_runtime.h>

// Problem constants
#define B_    8
#define CIN_  16
#define COUT_ 16
#define KS_   13
#define AS_   12
#define P_    4096
#define R_    12
#define M_    192          // COUT_ * R_
#define KTOT  2496         // CIN_ * KS_ * AS_   (reduction dim)
#define BN    128          // p-tile per workgroup (256 WGs, 1/CU)
#define KT    96           // K-tile (8 (c,k) pairs x 12 a)
#define NSTEP 26           // KTOT / KT (even -> clean 2-unroll)
#define LDP   104          // LDS pitch (96 + 8 pad)

typedef float  f32x4  __attribute__((ext_vector_type(4)));
typedef __bf16 bf16x4 __attribute__((ext_vector_type(4)));
typedef __bf16 bf16x8 __attribute__((ext_vector_type(8)));

// ---------------------------------------------------------------------------
// Kernel 1: expand W (16x16x36) -> Wmat[m=(d*12+r)][kappa=(c*13+k)*12+a] bf16
// Wfull[d,c,r,k,a] = W[d,c, idx_map[ tivr[r,k]*12 + tir[r,a] ]]
// ---------------------------------------------------------------------------
__global__ void build_wmat(const float* __restrict__ W,
                           const int* __restrict__ idx_map,
                           const int* __restrict__ tivr,   // [12][13]
                           const int* __restrict__ tir,    // [12][12]
                           __bf16* __restrict__ Wmat) {
  int m = blockIdx.x;            // 0..191
  int d = m / R_;
  int r = m - d * R_;
  for (int kap = threadIdx.x; kap < KTOT; kap += blockDim.x) {
    int c = kap / (KS_ * AS_);
    int t = kap - c * (KS_ * AS_);
    int k = t / AS_;
    int a = t - k * AS_;
    int s = idx_map[tivr[r * KS_ + k] * AS_ + tir[r * AS_ + a]];
    Wmat[m * KTOT + kap] = (__bf16)W[(d * CIN_ + c) * 36 + s];
  }
}

// ---------------------------------------------------------------------------
// Kernel 2: out(b,d,p,r) = Wmat(192 x 2496) @ Xmat(2496 x [b,p])
// 256 WGs x 512 threads, BM=192 (x read exactly once from HBM).
// LDS DOUBLE-BUFFERED: per step, ds_writes of tile kt+1 (into buf 1-c) and
// global issues of tile kt+2 overlap the MFMA on buf c. ONE barrier per step
// (lgkmcnt(0) + bare s_barrier). No vmcnt(0) drain anywhere in the loop.
// ---------------------------------------------------------------------------
__global__ __launch_bounds__(512, 2)
void s2conv(const float* __restrict__ x,
            const __bf16* __restrict__ Wmat,
            float* __restrict__ out) {
  __shared__ __bf16 Ws[2][M_][LDP];   // A tiles: 2 x 39.9 KB
  __shared__ __bf16 Xs[2][BN][LDP];   // B tiles: 2 x 26.6 KB   (total 133 KB)

  const int tid  = threadIdx.x;
  const int lane = tid & 63;
  const int wave = tid >> 6;        // 0..7
  const int wm   = wave >> 2;       // 0..1  (96 m-rows each)
  const int wn   = wave & 3;        // 0..3  (32 p-cols each)
  const int l15  = lane & 15;
  const int l4   = lane >> 4;

  const int wg = blockIdx.x;        // 0..255
  const int b  = wg >> 5;           // 0..7
  const int p0 = (wg & 31) << 7;    // p tile base

  f32x4 acc[6][2];
#pragma unroll
  for (int i = 0; i < 6; ++i)
#pragma unroll
    for (int j = 0; j < 2; ++j)
      acc[i][j] = f32x4{0.f, 0.f, 0.f, 0.f};

  // ---- staging helpers (explicit register sets, statically indexed) --------
  auto load_x = [&](int kt, f32x4 (&st)[6]) {
    // wave handles (c,k) pair ck = kt*8 + wave:
    // contiguous span x[b,c,k, p0:p0+128, 0:12] = 1536 floats = 384 float4
    int ck = kt * 8 + wave;
    const f32x4* bp =
        (const f32x4*)(x + (size_t)(b * 208 + ck) * 49152 + (size_t)p0 * 12);
#pragma unroll
    for (int it = 0; it < 6; ++it) st[it] = bp[it * 64 + lane];
  };

  auto load_w = [&](int kt, bf16x8 (&wst)[5]) {
    // 192 rows x 12 chunks of 8 bf16 (16B) = 2304 chunks
    const char* wb = (const char*)Wmat + (size_t)kt * (KT * 2);
#pragma unroll
    for (int j = 0; j < 5; ++j) {
      int i = tid + j * 512;
      if (i < 2304) {
        int row = i / 12;
        int chunk = i - row * 12;
        wst[j] = *(const bf16x8*)(wb + (size_t)row * (KTOT * 2) + chunk * 16);
      }
    }
  };

  auto write_tiles = [&](int buf, f32x4 (&st)[6], bf16x8 (&wst)[5]) {
    char* wsb = (char*)&Ws[buf][0][0];
    char* xsb = (char*)&Xs[buf][0][0];
#pragma unroll
    for (int j = 0; j < 5; ++j) {
      int i = tid + j * 512;
      if (i < 2304) {
        int row = i / 12;
        int chunk = i - row * 12;
        *(bf16x8*)(wsb + row * (LDP * 2) + chunk * 16) = wst[j];
      }
    }
#pragma unroll
    for (int it = 0; it < 6; ++it) {
      int f4i = it * 64 + lane;          // float4 index in this (c,k) span
      int pl  = f4i / 3;                 // p_local (float offset /12)
      int a   = (f4i - pl * 3) * 4;      // a in {0,4,8}
      bf16x4 v = __builtin_convertvector(st[it], bf16x4);
      *(bf16x4*)(xsb + pl * (LDP * 2) + (wave * 12 + a) * 2) = v;
    }
  };

  auto mfma_step = [&](int buf) {
    const __bf16* wsb = &Ws[buf][0][0];
    const __bf16* xsb = &Xs[buf][0][0];
#pragma unroll
    for (int ks = 0; ks < 3; ++ks) {     // 3 x K=32
      const int col = ks * 32 + l4 * 8;
      bf16x8 af[6], bfr[2];
#pragma unroll
      for (int mt = 0; mt < 6; ++mt)
        af[mt] = *(const bf16x8*)(wsb + (wm * 96 + mt * 16 + l15) * LDP + col);
#pragma unroll
      for (int nt = 0; nt < 2; ++nt)
        bfr[nt] = *(const bf16x8*)(xsb + (wn * 32 + nt * 16 + l15) * LDP + col);
#pragma unroll
      for (int mt = 0; mt < 6; ++mt)
#pragma unroll
        for (int nt = 0; nt < 2; ++nt)
          acc[mt][nt] = __builtin_amdgcn_mfma_f32_16x16x32_bf16(
              af[mt], bfr[nt], acc[mt][nt], 0, 0, 0);
    }
  };

  auto barrier = [&]() {
    asm volatile("s_waitcnt lgkmcnt(0)" ::: "memory");  // writes visible
    __builtin_amdgcn_s_barrier();                        // NO vmcnt drain
  };

  // ---- body: issue kt+2 into set I; write kt+1 (set W) into buf 1-c; ------
  //            MFMA on buf c; barrier.
  auto body = [&](int kt, f32x4 (&stI)[6], bf16x8 (&wstI)[5],
                  f32x4 (&stW)[6], bf16x8 (&wstW)[5]) {
    if (kt + 2 < NSTEP) { load_x(kt + 2, stI); load_w(kt + 2, wstI); }
    if (kt + 1 < NSTEP) write_tiles(1 - (kt & 1), stW, wstW);
    mfma_step(kt & 1);
    barrier();
  };

  // ---- prologue ------------------------------------------------------------
  f32x4  stA[6], stB[6];
  bf16x8 wstA[5], wstB[5];
  load_x(0, stA); load_w(0, wstA);
  load_x(1, stB); load_w(1, wstB);
  write_tiles(0, stA, wstA);
  barrier();

  // ---- main loop: x(j)/W(j) live in set (j&1); buf (j&1) holds tile j ------
  for (int kt = 0; kt < NSTEP; kt += 2) {
    body(kt,     stA, wstA, stB, wstB);  // issue kt+2->A, write kt+1 (B), mfma buf0
    body(kt + 1, stB, wstB, stA, wstA);  // issue kt+3->B, write kt+2 (A), mfma buf1
  }

  // ---- epilogue: store. m = d*12+r, lane's 4 regs = 4 consecutive r --------
#pragma unroll
  for (int mt = 0; mt < 6; ++mt) {
    int mrow0 = wm * 96 + mt * 16 + l4 * 4;   // r0 in {0,4,8} -> same d
    int d  = mrow0 / 12;
    int r0 = mrow0 - d * 12;
#pragma unroll
    for (int nt = 0; nt < 2; ++nt) {
      int p = p0 + wn * 32 + nt * 16 + l15;
      float* dst = out + (size_t)((b * 16 + d) * 4096 + p) * 12 + r0;
      *(f32x4*)dst = acc[mt][nt];   // 16B aligned: r0 in {0,4,8}
    }
  }
}

// ---------------------------------------------------------------------------
extern "C" void kernel_launch(void* const* d_in, const int* in_sizes, int n_in,
                              void* d_out, int out_size, void* d_ws, size_t ws_size,
                              hipStream_t stream) {
  const float* x       = (const float*)d_in[0];  // (8,16,13,4096,12) f32
  const float* W       = (const float*)d_in[1];  // (16,16,36) f32
  const int*   idx_map = (const int*)d_in[2];    // (156,)
  const int*   tivr    = (const int*)d_in[3];    // (12,13)
  const int*   tir     = (const int*)d_in[4];    // (12,12)
  float*       out     = (float*)d_out;          // (8,16,4096,12) f32
  __bf16*      Wmat    = (__bf16*)d_ws;          // 192*2496 bf16 = 958 KB

  build_wmat<<<dim3(M_), dim3(256), 0, stream>>>(W, idx_map, tivr, tir, Wmat);
  s2conv<<<dim3(256), dim3(512), 0, stream>>>(x, Wmat, out);
}

// Round 5
// 78.075 us; speedup vs baseline: 1.0876x; 1.0876x over previous
//
#include <hip/hip_runtime.h>

// Problem constants
#define B_    8
#define CIN_  16
#define COUT_ 16
#define KS_   13
#define AS_   12
#define P_    4096
#define R_    12
#define M_    192          // COUT_ * R_
#define KTOT  2496         // CIN_ * KS_ * AS_   (reduction dim)
#define BN    128          // p-tile per workgroup (256 WGs, 1/CU)
#define KT    96           // K-tile (8 (c,k) pairs x 12 a)
#define NSTEP 26           // KTOT / KT
#define LDP   104          // LDS pitch (96 + 8 pad)

typedef float  f32x4  __attribute__((ext_vector_type(4)));
typedef __bf16 bf16x4 __attribute__((ext_vector_type(4)));
typedef __bf16 bf16x8 __attribute__((ext_vector_type(8)));

// ---------------------------------------------------------------------------
// Kernel 1: expand W (16x16x36) -> Wmat[m=(d*12+r)][kappa=(c*13+k)*12+a] bf16
// ---------------------------------------------------------------------------
__global__ void build_wmat(const float* __restrict__ W,
                           const int* __restrict__ idx_map,
                           const int* __restrict__ tivr,   // [12][13]
                           const int* __restrict__ tir,    // [12][12]
                           __bf16* __restrict__ Wmat) {
  int m = blockIdx.x;            // 0..191
  int d = m / R_;
  int r = m - d * R_;
  for (int kap = threadIdx.x; kap < KTOT; kap += blockDim.x) {
    int c = kap / (KS_ * AS_);
    int t = kap - c * (KS_ * AS_);
    int k = t / AS_;
    int a = t - k * AS_;
    int s = idx_map[tivr[r * KS_ + k] * AS_ + tir[r * AS_ + a]];
    Wmat[m * KTOT + kap] = (__bf16)W[(d * CIN_ + c) * 36 + s];
  }
}

// ---------------------------------------------------------------------------
// Kernel 2: out(b,d,p,r) = Wmat(192 x 2496) @ Xmat(2496 x [b,p])
// 256 WGs x 512 threads, BM=192 (x read exactly once from HBM).
// LDS double-buffered; ALL global loads unconditional (4xb128+1xb64 W split,
// peeled loop tail) so the compiler emits COUNTED vmcnt waits, never vmcnt(0).
// One lgkmcnt(0)+s_barrier per step.
// ---------------------------------------------------------------------------
__global__ __launch_bounds__(512, 2)
void s2conv(const float* __restrict__ x,
            const __bf16* __restrict__ Wmat,
            float* __restrict__ out) {
  __shared__ __bf16 Ws[2][M_][LDP];   // A tiles: 2 x 39.9 KB
  __shared__ __bf16 Xs[2][BN][LDP];   // B tiles: 2 x 26.6 KB  (130 KB total)

  const int tid  = threadIdx.x;
  const int lane = tid & 63;
  const int wave = tid >> 6;        // 0..7
  const int wm   = wave >> 2;       // 0..1  (96 m-rows each)
  const int wn   = wave & 3;        // 0..3  (32 p-cols each)
  const int l15  = lane & 15;
  const int l4   = lane >> 4;

  const int wg = blockIdx.x;        // 0..255
  const int b  = wg >> 5;           // 0..7
  const int p0 = (wg & 31) << 7;    // p tile base

  // W-staging index precompute (thread-fixed)
  int wrow[4], wchk[4];
#pragma unroll
  for (int j = 0; j < 4; ++j) {
    int i = tid + j * 512;          // 0..2047
    wrow[j] = i / 12;
    wchk[j] = i - wrow[j] * 12;
  }
  const int ti   = 2048 + (tid >> 1);   // tail chunk 2048..2303
  const int trow = ti / 12;
  const int tchk = ti - trow * 12;
  const int thalf = (tid & 1) * 8;      // byte offset within 16B chunk

  f32x4 acc[6][2];
#pragma unroll
  for (int i = 0; i < 6; ++i)
#pragma unroll
    for (int j = 0; j < 2; ++j)
      acc[i][j] = f32x4{0.f, 0.f, 0.f, 0.f};

  // ---- staging (ALL loads unconditional) -----------------------------------
  auto load_x = [&](int kt, f32x4 (&st)[6]) {
    int ck = kt * 8 + wave;   // wave's (c,k) pair: contiguous 6 KB span
    const f32x4* bp =
        (const f32x4*)(x + (size_t)(b * 208 + ck) * 49152 + (size_t)p0 * 12);
#pragma unroll
    for (int it = 0; it < 6; ++it) st[it] = bp[it * 64 + lane];
  };

  auto load_w = [&](int kt, bf16x8 (&w4)[4], bf16x4& wt) {
    const char* wb = (const char*)Wmat + (size_t)kt * (KT * 2);
#pragma unroll
    for (int j = 0; j < 4; ++j)
      w4[j] = *(const bf16x8*)(wb + (size_t)wrow[j] * (KTOT * 2) + wchk[j] * 16);
    wt = *(const bf16x4*)(wb + (size_t)trow * (KTOT * 2) + tchk * 16 + thalf);
  };

  auto write_tiles = [&](int buf, f32x4 (&st)[6], bf16x8 (&w4)[4], bf16x4& wt) {
    char* wsb = (char*)&Ws[buf][0][0];
    char* xsb = (char*)&Xs[buf][0][0];
#pragma unroll
    for (int j = 0; j < 4; ++j)
      *(bf16x8*)(wsb + wrow[j] * (LDP * 2) + wchk[j] * 16) = w4[j];
    *(bf16x4*)(wsb + trow * (LDP * 2) + tchk * 16 + thalf) = wt;
#pragma unroll
    for (int it = 0; it < 6; ++it) {
      int f4i = it * 64 + lane;          // float4 index in this (c,k) span
      int pl  = f4i / 3;                 // p_local
      int a   = (f4i - pl * 3) * 4;      // a in {0,4,8}
      bf16x4 v = __builtin_convertvector(st[it], bf16x4);
      *(bf16x4*)(xsb + pl * (LDP * 2) + (wave * 12 + a) * 2) = v;
    }
  };

  auto mfma_step = [&](int buf) {
    const __bf16* wsb = &Ws[buf][0][0];
    const __bf16* xsb = &Xs[buf][0][0];
#pragma unroll
    for (int ks = 0; ks < 3; ++ks) {     // 3 x K=32
      const int col = ks * 32 + l4 * 8;
      bf16x8 af[6], bfr[2];
#pragma unroll
      for (int mt = 0; mt < 6; ++mt)
        af[mt] = *(const bf16x8*)(wsb + (wm * 96 + mt * 16 + l15) * LDP + col);
#pragma unroll
      for (int nt = 0; nt < 2; ++nt)
        bfr[nt] = *(const bf16x8*)(xsb + (wn * 32 + nt * 16 + l15) * LDP + col);
#pragma unroll
      for (int mt = 0; mt < 6; ++mt)
#pragma unroll
        for (int nt = 0; nt < 2; ++nt)
          acc[mt][nt] = __builtin_amdgcn_mfma_f32_16x16x32_bf16(
              af[mt], bfr[nt], acc[mt][nt], 0, 0, 0);
    }
  };

  auto barrier = [&]() {
    asm volatile("s_waitcnt lgkmcnt(0)" ::: "memory");  // LDS writes visible
    __builtin_amdgcn_s_barrier();                        // NO vmcnt drain
  };

  // ---- prologue ------------------------------------------------------------
  f32x4  stA[6], stB[6];
  bf16x8 wA4[4], wB4[4];
  bf16x4 wAt, wBt;
  load_x(0, stA); load_w(0, wA4, wAt);
  load_x(1, stB); load_w(1, wB4, wBt);
  write_tiles(0, stA, wA4, wAt);
  barrier();

  // ---- main loop: 12 iterations, NO conditional loads ----------------------
  for (int kt = 0; kt < NSTEP - 2; kt += 2) {
    load_x(kt + 2, stA); load_w(kt + 2, wA4, wAt);   // tile kt+2 -> set A
    __builtin_amdgcn_sched_barrier(0);
    write_tiles(1, stB, wB4, wBt);                   // tile kt+1 -> buf 1
    mfma_step(0);                                    // tile kt   (buf 0)
    barrier();

    load_x(kt + 3, stB); load_w(kt + 3, wB4, wBt);   // tile kt+3 -> set B
    __builtin_amdgcn_sched_barrier(0);
    write_tiles(0, stA, wA4, wAt);                   // tile kt+2 -> buf 0
    mfma_step(1);                                    // tile kt+1 (buf 1)
    barrier();
  }

  // ---- peeled tail: tiles 24 (buf 0) and 25 (regs B), no loads -------------
  write_tiles(1, stB, wB4, wBt);                     // tile 25 -> buf 1
  mfma_step(0);                                      // tile 24
  barrier();
  mfma_step(1);                                      // tile 25

  // ---- epilogue: store. m = d*12+r, lane's 4 regs = 4 consecutive r --------
#pragma unroll
  for (int mt = 0; mt < 6; ++mt) {
    int mrow0 = wm * 96 + mt * 16 + l4 * 4;   // r0 in {0,4,8} -> same d
    int d  = mrow0 / 12;
    int r0 = mrow0 - d * 12;
#pragma unroll
    for (int nt = 0; nt < 2; ++nt) {
      int p = p0 + wn * 32 + nt * 16 + l15;
      float* dst = out + (size_t)((b * 16 + d) * 4096 + p) * 12 + r0;
      *(f32x4*)dst = acc[mt][nt];   // 16B aligned: r0 in {0,4,8}
    }
  }
}

// ---------------------------------------------------------------------------
extern "C" void kernel_launch(void* const* d_in, const int* in_sizes, int n_in,
                              void* d_out, int out_size, void* d_ws, size_t ws_size,
                              hipStream_t stream) {
  const float* x       = (const float*)d_in[0];  // (8,16,13,4096,12) f32
  const float* W       = (const float*)d_in[1];  // (16,16,36) f32
  const int*   idx_map = (const int*)d_in[2];    // (156,)
  const int*   tivr    = (const int*)d_in[3];    // (12,13)
  const int*   tir     = (const int*)d_in[4];    // (12,12)
  float*       out     = (float*)d_out;          // (8,16,4096,12) f32
  __bf16*      Wmat    = (__bf16*)d_ws;          // 192*2496 bf16 = 958 KB

  build_wmat<<<dim3(M_), dim3(256), 0, stream>>>(W, idx_map, tivr, tir, Wmat);
  s2conv<<<dim3(256), dim3(512), 0, stream>>>(x, Wmat, out);
}